// Round 6
// baseline (267.382 us; speedup 1.0000x reference)
//
#include <hip/hip_runtime.h>
#include <cstdint>
#include <cstddef>

#define N_COLS 4096
#define TPB 256
#define WPB 4                 // waves per block; one row per wave, no barriers
#define NBINS 256
#define SURV_CAP 64

typedef float v4f __attribute__((ext_vector_type(4)));
__device__ __forceinline__ void store_nt(float4* p, const float4& v) {
    __builtin_nontemporal_store(*(const v4f*)&v, (v4f*)p);
}

// --- kernel 1: boost factors, double-precision exp rounded to fp32 ---
__global__ void boost_kernel(const float* __restrict__ dc,
                             const int* __restrict__ kp,
                             float* __restrict__ bf) {
    int i = blockIdx.x * blockDim.x + threadIdx.x;
    if (i < N_COLS) {
        float td = (float)kp[0] / (float)N_COLS;   // float32(k)/float32(n), like ref
        float arg = td - dc[i];                    // fp32 subtract, like ref
        bf[i] = (float)exp((double)arg);           // ~correctly-rounded fp32 exp
    }
}

__device__ __forceinline__ uint32_t orderable(uint32_t u) {
    return (u & 0x80000000u) ? ~u : (u | 0x80000000u);  // float order == uint order
}

// one wave per row; 64 elements per lane; all LDS wave-private; zero barriers
__global__ __launch_bounds__(TPB, 6) void kwinner_kernel(
    const float* __restrict__ x, const float* __restrict__ bf,
    const int* __restrict__ kp, float* __restrict__ out, int rows)
{
    __shared__ uint32_t s_hist[WPB][NBINS];    // 4 KB, per-wave regions
    __shared__ uint32_t s_cand[WPB][SURV_CAP]; // 1 KB
    __shared__ uint32_t s_m2[WPB];

    const int tid  = threadIdx.x;
    const int wid  = tid >> 6;
    const int lane = tid & 63;
    const int row  = (int)blockIdx.x * WPB + wid;
    if (row >= rows) return;                   // whole-wave exit; no barriers exist

    uint32_t* hist = s_hist[wid];
    uint32_t* cand = s_cand[wid];
    const float4* xr = (const float4*)(x + (size_t)row * N_COLS);
    const float4* br = (const float4*)bf;
    float4* orow = (float4*)(out + (size_t)row * N_COLS);

    // clear own histogram region + survivor counter (wave-private)
    { uint4 z; z.x = z.y = z.z = z.w = 0u; ((uint4*)hist)[lane] = z; }
    if (lane == 0) s_m2[wid] = 0;
    __threadfence_block();   // order clears before this wave's atomics

    // pass 1: histogram of candidates >= T0 with composite digit
    // d = min((bits>>16) - 0x3F80, 255): monotone for all floats >= 1.0.
    const float T0f = 1.10f;   // perf heuristic only; exactness guarded below
    #pragma unroll 4
    for (int j = 0; j < 16; ++j) {
        float4 a = xr[lane + j * 64];
        float4 b = br[lane + j * 64];
        float p[4] = {a.x * b.x, a.y * b.y, a.z * b.z, a.w * b.w};
        #pragma unroll
        for (int q = 0; q < 4; ++q) {
            if (p[q] >= T0f) {
                uint32_t d = (__float_as_uint(p[q]) >> 16) - 0x3F80u;
                d = d > 255u ? 255u : d;
                atomicAdd(&hist[d], 1u);
            }
        }
    }
    __threadfence_block();   // this wave's atomics complete before reads

    const uint32_t k = (uint32_t)kp[0];
    uint32_t rem = k;

    // per-wave suffix-scan + digit pick over own 256-bin histogram
    uint32_t pk;
    {
        uint4 v = ((const uint4*)hist)[lane];
        uint32_t s3 = v.w, s2 = v.z + s3, s1 = v.y + s2, s0 = v.x + s1;
        uint32_t T = s0;
        #pragma unroll
        for (int off = 1; off < 64; off <<= 1) {
            uint32_t t = (uint32_t)__shfl_down((int)T, off, 64);
            if (lane + off < 64) T += t;
        }
        uint32_t Tex = T - s0;   // sum over lanes > lane
        uint32_t S0 = Tex + s0, S1 = Tex + s1, S2 = Tex + s2, S3 = Tex + s3;
        int b = -1; uint32_t sn = 0;
        if (S3 >= rem)      { b = 3; sn = S3 - v.w; }
        else if (S2 >= rem) { b = 2; sn = S2 - v.z; }
        else if (S1 >= rem) { b = 1; sn = S1 - v.y; }
        else if (S0 >= rem) { b = 0; sn = S0 - v.x; }
        pk = (b >= 0) ? ((((uint32_t)(4 * lane + b + 1)) << 16) | sn) : 0u;
        #pragma unroll
        for (int off = 1; off < 64; off <<= 1) {
            uint32_t o = (uint32_t)__shfl_xor((int)pk, off, 64);
            pk = pk > o ? pk : o;
        }
        rem -= (pk & 0xFFFFu);
    }
    const uint32_t dsel = (pk >> 16) - 1u;
    bool fb = (pk == 0u) || (dsel == 255u);    // wave-uniform
    float thr = 0.0f;

    if (!fb) {
        const uint32_t hi16 = 0x3F80u + dsel;
        // pass 2: recompute boosted (bit-identical mult), scatter survivors of
        // the selected hi16 bin; may include sub-T0 bin-mates — all strictly
        // below every histogrammed member, and rem <= member count, so the
        // rem-th largest is unaffected (exact).
        #pragma unroll 4
        for (int j = 0; j < 16; ++j) {
            float4 a = xr[lane + j * 64];
            float4 b = br[lane + j * 64];
            float p[4] = {a.x * b.x, a.y * b.y, a.z * b.z, a.w * b.w};
            #pragma unroll
            for (int q = 0; q < 4; ++q) {
                uint32_t ub = __float_as_uint(p[q]);
                if ((ub >> 16) == hi16) {
                    uint32_t pos = atomicAdd(&s_m2[wid], 1u);
                    if (pos < SURV_CAP) cand[pos] = ub;
                }
            }
        }
        __threadfence_block();
        const uint32_t m2 = s_m2[wid];         // wave-uniform
        if (m2 <= SURV_CAP) {
            // 16-bit ballot descent within this wave (== this row)
            uint32_t cv = ((uint32_t)lane < m2) ? cand[lane] : ((~hi16) << 16);
            uint32_t cur = 0;
            #pragma unroll
            for (int bpos = 15; bpos >= 0; --bpos) {
                uint32_t t  = (hi16 << 16) | cur | (1u << bpos);
                uint32_t mk = ~((1u << bpos) - 1u);
                uint32_t c  = (uint32_t)__popcll(__ballot(((cv ^ t) & mk) == 0u));
                if (c >= rem) cur |= (1u << bpos);
                else          rem -= c;
            }
            thr = __uint_as_float((hi16 << 16) | cur);
        } else {
            fb = true;
        }
    }

    if (fb) {
        // adversarial-data fallback: exact per-wave 4-pass orderable radix
        uint32_t prefix = 0;
        rem = k;
        const uint32_t pmasks[4] = {0u, 0xFF000000u, 0xFFFF0000u, 0xFFFFFF00u};
        #pragma unroll 1
        for (int pass = 0; pass < 4; ++pass) {
            { uint4 z; z.x = z.y = z.z = z.w = 0u; ((uint4*)hist)[lane] = z; }
            __threadfence_block();
            const int shift = 24 - pass * 8;
            const uint32_t pm = pmasks[pass];
            #pragma unroll 2
            for (int j = 0; j < 16; ++j) {
                float4 a = xr[lane + j * 64];
                float4 b = br[lane + j * 64];
                float p[4] = {a.x * b.x, a.y * b.y, a.z * b.z, a.w * b.w};
                #pragma unroll
                for (int q = 0; q < 4; ++q) {
                    uint32_t ou = orderable(__float_as_uint(p[q]));
                    if (((ou ^ prefix) & pm) == 0u)
                        atomicAdd(&hist[(ou >> shift) & 255u], 1u);
                }
            }
            __threadfence_block();
            uint4 v = ((const uint4*)hist)[lane];
            uint32_t s3 = v.w, s2 = v.z + s3, s1 = v.y + s2, s0 = v.x + s1;
            uint32_t T = s0;
            #pragma unroll
            for (int off = 1; off < 64; off <<= 1) {
                uint32_t t = (uint32_t)__shfl_down((int)T, off, 64);
                if (lane + off < 64) T += t;
            }
            uint32_t Tex = T - s0;
            uint32_t S0 = Tex + s0, S1 = Tex + s1, S2 = Tex + s2, S3 = Tex + s3;
            int b = -1; uint32_t sn = 0;
            if (S3 >= rem)      { b = 3; sn = S3 - v.w; }
            else if (S2 >= rem) { b = 2; sn = S2 - v.z; }
            else if (S1 >= rem) { b = 1; sn = S1 - v.y; }
            else if (S0 >= rem) { b = 0; sn = S0 - v.x; }
            uint32_t pk2 = (b >= 0) ? ((((uint32_t)(4 * lane + b + 1)) << 16) | sn) : 0u;
            #pragma unroll
            for (int off = 1; off < 64; off <<= 1) {
                uint32_t o = (uint32_t)__shfl_xor((int)pk2, off, 64);
                pk2 = pk2 > o ? pk2 : o;
            }
            prefix |= ((pk2 >> 16) - 1u) << shift;
            rem -= (pk2 & 0xFFFFu);
            __threadfence_block();   // scan reads done before next pass clears
        }
        uint32_t tu = (prefix & 0x80000000u) ? (prefix & 0x7FFFFFFFu) : ~prefix;
        thr = __uint_as_float(tu);
    }

    // pass 3: recompute boosted (bit-identical), mask x, nontemporal store
    #pragma unroll 4
    for (int j = 0; j < 16; ++j) {
        float4 a = xr[lane + j * 64];
        float4 b = br[lane + j * 64];
        float4 o;
        o.x = (a.x * b.x >= thr) ? a.x : 0.0f;
        o.y = (a.y * b.y >= thr) ? a.y : 0.0f;
        o.z = (a.z * b.z >= thr) ? a.z : 0.0f;
        o.w = (a.w * b.w >= thr) ? a.w : 0.0f;
        store_nt(&orow[lane + j * 64], o);
    }
}

extern "C" void kernel_launch(void* const* d_in, const int* in_sizes, int n_in,
                              void* d_out, int out_size, void* d_ws, size_t ws_size,
                              hipStream_t stream) {
    const float* x  = (const float*)d_in[0];
    const float* dc = (const float*)d_in[1];
    const int*   kp = (const int*)d_in[2];
    float* out = (float*)d_out;
    float* bf  = (float*)d_ws;                 // 4096 floats of scratch

    const int n    = in_sizes[1];              // 4096
    const int rows = in_sizes[0] / n;          // 8192

    boost_kernel<<<(n + TPB - 1) / TPB, TPB, 0, stream>>>(dc, kp, bf);
    kwinner_kernel<<<(rows + WPB - 1) / WPB, TPB, 0, stream>>>(x, bf, kp, out, rows);
}